// Round 9
// baseline (773.406 us; speedup 1.0000x reference)
//
#include <hip/hip_runtime.h>

#define NB 2
#define D 32
#define H 128
#define NSTEPS 8
#define BT 256

typedef _Float16 f16;
typedef _Float16 f16x2 __attribute__((ext_vector_type(2)));
typedef _Float16 f16x8 __attribute__((ext_vector_type(8)));
typedef float    f32x4 __attribute__((ext_vector_type(4)));
typedef unsigned int uint;
typedef uint uintx4 __attribute__((ext_vector_type(4)));

// Weights/biases feeding a tanh are pre-scaled by 2*log2(e) at staging time, so
// the MFMA accumulator is already v = 2*log2e*z and tanh needs no multiply:
#define TSCL 2.8853900817779268f

__device__ __forceinline__ uint pku(float a, float b) {
    return __builtin_bit_cast(uint, __builtin_amdgcn_cvt_pkrtz(a, b));
}
__device__ __forceinline__ float lo32(uint u) { return (float)__builtin_bit_cast(f16x2, u)[0]; }
__device__ __forceinline__ float hi32(uint u) { return (float)__builtin_bit_cast(f16x2, u)[1]; }

// Batched-reciprocal tanh: 8 prescaled values -> 4 packed-f16 dwords.
// tanh(z) = 1 - 2/(1+2^v). Per 4-group: ONE v_rcp on the product replaces 4
// rcps (1/q_i = (prod_{j!=i} q_j) * rcp(prod q_j)). 16 trans -> 10 trans per
// 8 tanh (-96 cyc), +~38 full-rate (+76 cyc) => net -52 cyc / 8 tanh.
// Clamp v<=28: q<=1+2^28, 4-product <=5.2e33 < f32-max (no inf*0); tanh at
// v=28 is 1-7.4e-9 -> rounds to f16 1.0 exactly, so the clamp is lossless.
__device__ __forceinline__ void tanh8(const float v[8], uint o[4]) {
    float q[8];
    #pragma unroll
    for (int i = 0; i < 8; ++i)
        q[i] = __builtin_amdgcn_exp2f(fminf(v[i], 28.f)) + 1.f;
    #pragma unroll
    for (int g = 0; g < 2; ++g) {
        float q0 = q[4*g], q1 = q[4*g+1], q2 = q[4*g+2], q3 = q[4*g+3];
        float t01 = q0*q1, t23 = q2*q3;
        float R = __builtin_amdgcn_rcpf(t01*t23);
        float i0 = q1*t23*R, i1 = q0*t23*R, i2 = t01*q3*R, i3 = t01*q2*R;
        o[2*g+0] = pku(fmaf(-2.f, i0, 1.f), fmaf(-2.f, i1, 1.f));
        o[2*g+1] = pku(fmaf(-2.f, i2, 1.f), fmaf(-2.f, i3, 1.f));
    }
}

__device__ const float CC[6] = {0.f, 0.2f, 0.3f, 0.8f, 8.f/9.f, 1.f};

// BOTTLENECK MODEL (R0..R18 measured):
//  * Dual-sample ILP (R15): 747->710. L2/L3 fusion + direct B-frag (R16): 660.
//  * REGISTER REGIME LEDGER (closed — compiler-knob space exhausted):
//    - min-waves=2 in ANY spelling (LB(256,2), LB(256)+wpe(2,2), wpe(2,2)):
//      VGPR=128 + ~100MB spill, 2 blocks/CU -> 660-662 us. BEST KNOWN.
//    - min-waves=1 (wpe(1,2), no LB): VGPR=168, ZERO spill, but total
//      (arch+acc) > 256/wave -> 1 block/CU -> 870 us. Worse.
//    "No-spill + 2 blocks" needs total <=256/wave; working set misses it.
//  * Issue model @R8: ~5300 VALU cyc/wave/stage; 256 trans ops (128 exp2 +
//    128 rcp) ~= 4100 of it. LUT-tanh failed (R14: LDS gather conflicts).
//  * THIS ROUND: batched-reciprocal tanh (tanh8 above) — rcp count /4.
//    Predicted -830 cyc/wave-stage (-15% issue) -> ~580-615 us.
struct __align__(16) SMem {
    f16   W1f[8 * 64 * 8];     // [nt][lane][j]      : TSCL*W1[32+phi1(q,j)][nt*16+mr]
    f16   W2f[8 * 4 * 64 * 8]; // [nt][kt][lane][j]  : TSCL*W2[phi(kt,q,j)][nt*16+mr]
    f16   W3f[2 * 4 * 64 * 8]; // [nt][kt][lane][j]  : W3[phi(kt,q,j)][nt*16+mr] (unscaled)
    float B1[H], S1[H], B2[H], B3[D];   // B1,S1,B2 pre-scaled by TSCL
};

// phi(kt,q,j) = (2kt + j/4)*16 + q*4 + j%4 ; phi1(q,j) = (j/4)*16 + q*4 + j%4.
// Identical k-permutation on A (staged weights) and B (C-layout activations)
// -> MFMA k-sum invariant. Zero activation LDS traffic, zero shuffles.
//
// REGISTER MODEL (measured R3..R18):
//  * Inner weight loops stay at unroll<=2 / unroll 1 so ds_read fragments
//    don't hoist en masse (R4/R7: full unroll -> 7.4/7.6 GB spill).
//  * All register arrays indexed ONLY by fully unrolled vars — runtime
//    indexing demotes to scratch.

// DOPRI stage combines (per 2-elem packed lane j), parameterized by sample.
#define DOP0(x_, ksp_, by_, kd_) \
    _Pragma("unroll") for (int j = 0; j < 4; ++j) { \
        ksp_[0][j] = pku(kd_[2*j], kd_[2*j+1]); \
        float ya = fmaf(dt*0.2f, kd_[2*j],   x_[2*j]); \
        float yb = fmaf(dt*0.2f, kd_[2*j+1], x_[2*j+1]); \
        by_[j] = pku(ya, yb); }

#define DOP1(x_, ksp_, by_, kd_) \
    _Pragma("unroll") for (int j = 0; j < 4; ++j) { \
        ksp_[1][j] = pku(kd_[2*j], kd_[2*j+1]); \
        float ya = x_[2*j]   + dt*((3.f/40.f)*lo32(ksp_[0][j]) + (9.f/40.f)*kd_[2*j]); \
        float yb = x_[2*j+1] + dt*((3.f/40.f)*hi32(ksp_[0][j]) + (9.f/40.f)*kd_[2*j+1]); \
        by_[j] = pku(ya, yb); }

#define DOP2(x_, ksp_, by_, kd_) \
    _Pragma("unroll") for (int j = 0; j < 4; ++j) { \
        ksp_[2][j] = pku(kd_[2*j], kd_[2*j+1]); \
        float ya = x_[2*j]   + dt*((44.f/45.f)*lo32(ksp_[0][j]) - (56.f/15.f)*lo32(ksp_[1][j]) + (32.f/9.f)*kd_[2*j]); \
        float yb = x_[2*j+1] + dt*((44.f/45.f)*hi32(ksp_[0][j]) - (56.f/15.f)*hi32(ksp_[1][j]) + (32.f/9.f)*kd_[2*j+1]); \
        by_[j] = pku(ya, yb); }

#define DOP3(x_, ksp_, by_, kd_) \
    _Pragma("unroll") for (int j = 0; j < 4; ++j) { \
        ksp_[3][j] = pku(kd_[2*j], kd_[2*j+1]); \
        float ya = x_[2*j]   + dt*((19372.f/6561.f)*lo32(ksp_[0][j]) - (25360.f/2187.f)*lo32(ksp_[1][j]) \
                                + (64448.f/6561.f)*lo32(ksp_[2][j]) - (212.f/729.f)*kd_[2*j]); \
        float yb = x_[2*j+1] + dt*((19372.f/6561.f)*hi32(ksp_[0][j]) - (25360.f/2187.f)*hi32(ksp_[1][j]) \
                                + (64448.f/6561.f)*hi32(ksp_[2][j]) - (212.f/729.f)*kd_[2*j+1]); \
        by_[j] = pku(ya, yb); }

#define DOP4(x_, ksp_, by_, kd_) \
    _Pragma("unroll") for (int j = 0; j < 4; ++j) { \
        ksp_[4][j] = pku(kd_[2*j], kd_[2*j+1]); \
        float ya = x_[2*j]   + dt*((9017.f/3168.f)*lo32(ksp_[0][j]) - (355.f/33.f)*lo32(ksp_[1][j]) \
                                + (46732.f/5247.f)*lo32(ksp_[2][j]) + (49.f/176.f)*lo32(ksp_[3][j]) \
                                - (5103.f/18656.f)*kd_[2*j]); \
        float yb = x_[2*j+1] + dt*((9017.f/3168.f)*hi32(ksp_[0][j]) - (355.f/33.f)*hi32(ksp_[1][j]) \
                                + (46732.f/5247.f)*hi32(ksp_[2][j]) + (49.f/176.f)*hi32(ksp_[3][j]) \
                                - (5103.f/18656.f)*kd_[2*j+1]); \
        by_[j] = pku(ya, yb); }

#define DOP5(x_, ksp_, by_, kd_) \
    _Pragma("unroll") for (int j = 0; j < 4; ++j) { \
        float xa = x_[2*j]   + dt*((35.f/384.f)*lo32(ksp_[0][j]) + (500.f/1113.f)*lo32(ksp_[2][j]) \
                                + (125.f/192.f)*lo32(ksp_[3][j]) - (2187.f/6784.f)*lo32(ksp_[4][j]) \
                                + (11.f/84.f)*kd_[2*j]); \
        float xb = x_[2*j+1] + dt*((35.f/384.f)*hi32(ksp_[0][j]) + (500.f/1113.f)*hi32(ksp_[2][j]) \
                                + (125.f/192.f)*hi32(ksp_[3][j]) - (2187.f/6784.f)*hi32(ksp_[4][j]) \
                                + (11.f/84.f)*kd_[2*j+1]); \
        x_[2*j] = xa; x_[2*j+1] = xb; \
        by_[j] = pku(xa, xb); }

__global__
__attribute__((amdgpu_flat_work_group_size(256, 256), amdgpu_waves_per_eu(2, 2)))
void ffjord_mfma(
    const float* __restrict__ x_in,
    const float* __restrict__ W1, const float* __restrict__ b1,
    const float* __restrict__ W2, const float* __restrict__ b2,
    const float* __restrict__ W3, const float* __restrict__ b3,
    float* __restrict__ out)
{
    __shared__ SMem sm;

    const int tid  = threadIdx.x;
    const int lane = tid & 63;
    const int mrow = lane & 15;      // my sample within the wave tile
    const int quad = lane >> 4;      // k/feature quad
    const int wid  = tid >> 6;
    // Two samples per thread: A and B tiles are independent 16-sample MFMA
    // B-fragments sharing every weight fragment / C-init.
    const int sidxA = blockIdx.x * 128 + wid * 32 + mrow;
    const int sidxB = sidxA + 16;

    float xA[8], xB[8];
    uint  kspA[5][4], kspB[5][4];
    uint  byA[4], byB[4];

    #pragma unroll
    for (int nt = 0; nt < 2; ++nt) {
        f32x4 va = *(const f32x4*)(x_in + (size_t)sidxA*D + nt*16 + quad*4);
        f32x4 vb = *(const f32x4*)(x_in + (size_t)sidxB*D + nt*16 + quad*4);
        #pragma unroll
        for (int r = 0; r < 4; ++r) { xA[nt*4 + r] = va[r]; xB[nt*4 + r] = vb[r]; }
    }

    const float dt = 0.125f;

    for (int bij = 0; bij < NB; ++bij) {
        const float* W1b = W1 + (size_t)bij * 2*D*H;
        const float* b1b = b1 + bij*H;
        const float* W2b = W2 + (size_t)bij * H*H;
        const float* b2b = b2 + bij*H;
        const float* W3b = W3 + (size_t)bij * H*D;
        const float* b3b = b3 + bij*D;

        __syncthreads();  // prior bijector done reading weights
        // ---- stage weights: fragment-order, k-permuted, f16, tanh-prescaled ----
        #pragma unroll 1
        for (int g = tid; g < 8*64; g += BT) {               // W1f (x TSCL)
            int nt = g >> 6, ln = g & 63, q = (ln >> 4) & 3, mr = ln & 15;
            f16 tmp[8];
            #pragma unroll
            for (int j = 0; j < 8; ++j) {
                int feat = ((j >> 2) << 4) + q*4 + (j & 3);  // phi1
                tmp[j] = (f16)(W1b[(size_t)(D + feat)*H + nt*16 + mr] * TSCL);
            }
            *(f16x8*)&sm.W1f[(size_t)g * 8] = *(f16x8*)tmp;
        }
        #pragma unroll 1
        for (int g = tid; g < 8*4*64; g += BT) {             // W2f (x TSCL)
            int nt = g >> 8, kt = (g >> 6) & 3, ln = g & 63, q = (ln >> 4) & 3, mr = ln & 15;
            f16 tmp[8];
            #pragma unroll
            for (int j = 0; j < 8; ++j) {
                int feat = (2*kt + (j >> 2))*16 + q*4 + (j & 3);  // phi
                tmp[j] = (f16)(W2b[(size_t)feat*H + nt*16 + mr] * TSCL);
            }
            *(f16x8*)&sm.W2f[(size_t)g * 8] = *(f16x8*)tmp;
        }
        #pragma unroll 1
        for (int g = tid; g < 2*4*64; g += BT) {             // W3f (unscaled)
            int nt = g >> 8, kt = (g >> 6) & 3, ln = g & 63, q = (ln >> 4) & 3, mr = ln & 15;
            f16 tmp[8];
            #pragma unroll
            for (int j = 0; j < 8; ++j) {
                int feat = (2*kt + (j >> 2))*16 + q*4 + (j & 3);  // phi
                tmp[j] = (f16)W3b[(size_t)feat*D + nt*16 + mr];
            }
            *(f16x8*)&sm.W3f[(size_t)g * 8] = *(f16x8*)tmp;
        }
        #pragma unroll 1
        for (int n = tid; n < H; n += BT) {                  // biases + t-fold sums (x TSCL)
            float s = 0.f;
            for (int i = 0; i < D; ++i) s += W1b[(size_t)i*H + n];
            sm.S1[n] = s * TSCL; sm.B1[n] = b1b[n] * TSCL; sm.B2[n] = b2b[n] * TSCL;
        }
        if (tid < D) sm.B3[tid] = b3b[tid];
        __syncthreads();

        // y := x  (packed)
        #pragma unroll
        for (int p = 0; p < 4; ++p) {
            byA[p] = pku(xA[2*p], xA[2*p + 1]);
            byB[p] = pku(xB[2*p], xB[2*p + 1]);
        }

        for (int step = 0; step < NSTEPS; ++step) {
            const float t0 = step * dt;
            #pragma unroll 1
            for (int s = 0; s < 6; ++s) {
                const float te = t0 + dt * CC[s];

                // ======== EVAL: two samples share every weight fragment ========
                // layer 1 (K=32): C init = (b1 + te*S1)*TSCL. Output built
                // DIRECTLY as the 4 L2 B-fragments (frag ktg = L1 nt 2ktg,2ktg+1).
                f16x8 fA1[4], fB1[4];
                {
                    union { f16x8 v; uint u[4]; } ba, bb;
                    ba.u[0] = byA[0]; ba.u[1] = byA[1]; ba.u[2] = byA[2]; ba.u[3] = byA[3];
                    bb.u[0] = byB[0]; bb.u[1] = byB[1]; bb.u[2] = byB[2]; bb.u[3] = byB[3];
                    #pragma unroll
                    for (int ktg = 0; ktg < 4; ++ktg) {
                        float vA[8], vB[8];
                        #pragma unroll
                        for (int h = 0; h < 2; ++h) {
                            const int nt = ktg*2 + h;
                            f16x8 wf = *(const f16x8*)&sm.W1f[(nt*64 + lane)*8];
                            f32x4 bv = *(const f32x4*)&sm.B1[nt*16 + quad*4];
                            f32x4 sv = *(const f32x4*)&sm.S1[nt*16 + quad*4];
                            f32x4 ci;
                            #pragma unroll
                            for (int r = 0; r < 4; ++r) ci[r] = fmaf(te, sv[r], bv[r]);
                            f32x4 accA = __builtin_amdgcn_mfma_f32_16x16x32_f16(wf, ba.v, ci, 0, 0, 0);
                            f32x4 accB = __builtin_amdgcn_mfma_f32_16x16x32_f16(wf, bb.v, ci, 0, 0, 0);
                            #pragma unroll
                            for (int r = 0; r < 4; ++r) { vA[h*4+r] = accA[r]; vB[h*4+r] = accB[r]; }
                        }
                        uint da[4], db[4];
                        tanh8(vA, da);
                        tanh8(vB, db);
                        uintx4 ua = {da[0], da[1], da[2], da[3]};
                        uintx4 ub = {db[0], db[1], db[2], db[3]};
                        fA1[ktg] = __builtin_bit_cast(f16x8, ua);
                        fB1[ktg] = __builtin_bit_cast(f16x8, ub);
                    }
                }
                // layer 2 (K=128) with layer 3 FUSED: each completed ph2
                // fragment (per ktg) feeds its 4 L3 MFMAs immediately and dies.
                float kdA[8], kdB[8];
                {
                    f32x4 a3A[2], a3B[2];
                    #pragma unroll
                    for (int n3 = 0; n3 < 2; ++n3) {
                        f32x4 c = *(const f32x4*)&sm.B3[n3*16 + quad*4];
                        a3A[n3] = c; a3B[n3] = c;
                    }
                    #pragma unroll 1
                    for (int ktg = 0; ktg < 4; ++ktg) {
                        float vA[8], vB[8];
                        #pragma unroll
                        for (int h = 0; h < 2; ++h) {
                            const int nt = ktg*2 + h;
                            f32x4 c0 = *(const f32x4*)&sm.B2[nt*16 + quad*4];
                            f32x4 accA = c0, accB = c0;
                            #pragma unroll
                            for (int kt2 = 0; kt2 < 4; ++kt2) {
                                f16x8 wf = *(const f16x8*)&sm.W2f[((nt*4 + kt2)*64 + lane)*8];
                                accA = __builtin_amdgcn_mfma_f32_16x16x32_f16(wf, fA1[kt2], accA, 0, 0, 0);
                                accB = __builtin_amdgcn_mfma_f32_16x16x32_f16(wf, fB1[kt2], accB, 0, 0, 0);
                            }
                            #pragma unroll
                            for (int r = 0; r < 4; ++r) { vA[h*4+r] = accA[r]; vB[h*4+r] = accB[r]; }
                        }
                        uint da[4], db[4];
                        tanh8(vA, da);
                        tanh8(vB, db);
                        uintx4 ua = {da[0], da[1], da[2], da[3]};
                        uintx4 ub = {db[0], db[1], db[2], db[3]};
                        f16x8 fra = __builtin_bit_cast(f16x8, ua);
                        f16x8 frb = __builtin_bit_cast(f16x8, ub);
                        #pragma unroll
                        for (int n3 = 0; n3 < 2; ++n3) {
                            f16x8 wf3 = *(const f16x8*)&sm.W3f[((n3*4 + ktg)*64 + lane)*8];
                            a3A[n3] = __builtin_amdgcn_mfma_f32_16x16x32_f16(wf3, fra, a3A[n3], 0, 0, 0);
                            a3B[n3] = __builtin_amdgcn_mfma_f32_16x16x32_f16(wf3, frb, a3B[n3], 0, 0, 0);
                        }
                    }
                    #pragma unroll
                    for (int n3 = 0; n3 < 2; ++n3)
                        #pragma unroll
                        for (int r = 0; r < 4; ++r) {
                            kdA[n3*4 + r] = a3A[n3][r];
                            kdB[n3*4 + r] = a3B[n3][r];
                        }
                }

                // ===== DOPRI combine (both samples) =====
                switch (s) {
                case 0:  DOP0(xA, kspA, byA, kdA) DOP0(xB, kspB, byB, kdB) break;
                case 1:  DOP1(xA, kspA, byA, kdA) DOP1(xB, kspB, byB, kdB) break;
                case 2:  DOP2(xA, kspA, byA, kdA) DOP2(xB, kspB, byB, kdB) break;
                case 3:  DOP3(xA, kspA, byA, kdA) DOP3(xB, kspB, byB, kdB) break;
                case 4:  DOP4(xA, kspA, byA, kdA) DOP4(xB, kspB, byB, kdB) break;
                default: DOP5(xA, kspA, byA, kdA) DOP5(xB, kspB, byB, kdB) break;
                }
            } // stages
        } // steps
    } // bijectors

    #pragma unroll
    for (int nt = 0; nt < 2; ++nt) {
        f32x4 va, vb;
        #pragma unroll
        for (int r = 0; r < 4; ++r) { va[r] = xA[nt*4 + r]; vb[r] = xB[nt*4 + r]; }
        *(f32x4*)(out + (size_t)sidxA*D + nt*16 + quad*4) = va;
        *(f32x4*)(out + (size_t)sidxB*D + nt*16 + quad*4) = vb;
    }
}

extern "C" void kernel_launch(void* const* d_in, const int* in_sizes, int n_in,
                              void* d_out, int out_size, void* d_ws, size_t ws_size,
                              hipStream_t stream) {
    (void)d_ws; (void)ws_size; (void)n_in; (void)out_size;
    const float* x  = (const float*)d_in[0];
    const float* W1 = (const float*)d_in[1];
    const float* b1 = (const float*)d_in[2];
    const float* W2 = (const float*)d_in[3];
    const float* b2 = (const float*)d_in[4];
    const float* W3 = (const float*)d_in[5];
    const float* b3 = (const float*)d_in[6];
    float* out = (float*)d_out;

    const int n = in_sizes[0] / D;          // 65536 samples
    const int grid = n / 128;               // 512 blocks (128 samples each), exact
    ffjord_mfma<<<grid, BT, 0, stream>>>(x, W1, b1, W2, b2, W3, b3, out);
}

// Round 11
// 551.850 us; speedup vs baseline: 1.4015x; 1.4015x over previous
//
#include <hip/hip_runtime.h>

#define NB 2
#define D 32
#define H 128
#define NSTEPS 8
#define BT 256

typedef _Float16 f16;
typedef _Float16 f16x2 __attribute__((ext_vector_type(2)));
typedef _Float16 f16x8 __attribute__((ext_vector_type(8)));
typedef float    f32x4 __attribute__((ext_vector_type(4)));
typedef unsigned int uint;
typedef uint uintx4 __attribute__((ext_vector_type(4)));

// Weights/biases feeding a tanh are pre-scaled by 2*log2(e) at staging time, so
// the MFMA accumulator is already v = 2*log2e*z and tanh needs no multiply:
#define TSCL 2.8853900817779268f

__device__ __forceinline__ float fast_tanh_pre(float v) {
    // v = 2*log2e*z. tanh(z) = 1 - 2/(1+2^v); exp2 saturates -> exact +-1 limits.
    float e = __builtin_amdgcn_exp2f(v);
    return 1.f - 2.f * __builtin_amdgcn_rcpf(1.f + e);
}
__device__ __forceinline__ uint tanh_pk(float a, float b) {
    return __builtin_bit_cast(uint, __builtin_amdgcn_cvt_pkrtz(fast_tanh_pre(a), fast_tanh_pre(b)));
}
__device__ __forceinline__ uint pku(float a, float b) {
    return __builtin_bit_cast(uint, __builtin_amdgcn_cvt_pkrtz(a, b));
}
__device__ __forceinline__ float lo32(uint u) { return (float)__builtin_bit_cast(f16x2, u)[0]; }
__device__ __forceinline__ float hi32(uint u) { return (float)__builtin_bit_cast(f16x2, u)[1]; }

__device__ const float CC[6] = {0.f, 0.2f, 0.3f, 0.8f, 8.f/9.f, 1.f};

// BOTTLENECK MODEL (R0..R20 measured):
//  * Best known: R8/R16 structure = 662 us (VGPR pinned 128, ~110 MB HBM
//    scratch spill, 2 blocks/CU, VALUBusy ~61, MfmaUtil ~20).
//  * TRANS COST CALIBRATED BY R19 (tanh8 regression 662->773, VALU issue
//    +36%): trans ops ~8 cyc/wave64, NOT 16. So tanh = 2 trans + 2 full
//    = ~20 cyc; 128 tanh/thread-stage ~= 2560 of ~5300 VALU cyc/wave-stage
//    (48%) — irreducible (LUT R14 failed: gather conflicts; batched-rcp R19
//    failed: trans too cheap; Pade >= exp2 path).
//  * Spill ~= 13% of issue + latency: ~110 MB scratch write + 66 MB read
//    per dispatch at VGPR=128 (min-waves=2 regime; R17 proved natural need
//    is 168 -> ~40 regs spilled).
//  * R20: no data — container infra failure. This IS the R20 kernel, rerun.
//  * THEORY: manual "spill to LDS" — ksp[0..2] (both samples, 24
//    dwords/thread) moves to a conflict-free LDS stash (+24576 B/block;
//    75392 B total, 2 blocks = 150.8 KB <= 160 ✓). The compiler's HBM
//    scratch round-trips become cheap ds ops on the idle LDS pipe.
//    k3/k4 stay in registers. Eval path = R8's (direct tanh_pk from accs).
struct __align__(16) SMem {
    f16   W1f[8 * 64 * 8];     // [nt][lane][j]      : TSCL*W1[32+phi1(q,j)][nt*16+mr]
    f16   W2f[8 * 4 * 64 * 8]; // [nt][kt][lane][j]  : TSCL*W2[phi(kt,q,j)][nt*16+mr]
    f16   W3f[2 * 4 * 64 * 8]; // [nt][kt][lane][j]  : W3[phi(kt,q,j)][nt*16+mr] (unscaled)
    float B1[H], S1[H], B2[H], B3[D];   // B1,S1,B2 pre-scaled by TSCL
    uint  KS[3][2][4][BT];     // k1..k3 history stash [k-idx][sample][j][tid]
                               // lane-stride 4B -> conflict-free; private per
                               // thread -> NO barrier needed.
};

// phi(kt,q,j) = (2kt + j/4)*16 + q*4 + j%4 ; phi1(q,j) = (j/4)*16 + q*4 + j%4.
// Identical k-permutation on A (staged weights) and B (C-layout activations)
// -> MFMA k-sum invariant. Zero activation LDS traffic, zero shuffles.
//
// REGISTER MODEL (measured R3..R19):
//  * min-waves=2 (any spelling) -> VGPR=128 + spill; min-waves=1 -> 168,
//    no spill, but 1 block/CU (870 us). Compiler-knob space exhausted;
//    this round reduces the SPILLED SET instead (-24 persistent regs).
//  * Inner weight loops stay at unroll<=2 / unroll 1 (R4/R7: full unroll
//    -> GB-scale spill). Register arrays indexed only by unrolled vars.

__global__
__attribute__((amdgpu_flat_work_group_size(256, 256), amdgpu_waves_per_eu(2, 2)))
void ffjord_mfma(
    const float* __restrict__ x_in,
    const float* __restrict__ W1, const float* __restrict__ b1,
    const float* __restrict__ W2, const float* __restrict__ b2,
    const float* __restrict__ W3, const float* __restrict__ b3,
    float* __restrict__ out)
{
    __shared__ SMem sm;

    const int tid  = threadIdx.x;
    const int lane = tid & 63;
    const int mrow = lane & 15;      // my sample within the wave tile
    const int quad = lane >> 4;      // k/feature quad
    const int wid  = tid >> 6;
    // Two samples per thread: A and B tiles are independent 16-sample MFMA
    // B-fragments sharing every weight fragment / C-init.
    const int sidxA = blockIdx.x * 128 + wid * 32 + mrow;
    const int sidxB = sidxA + 16;

    float xA[8], xB[8];
    uint  k3A[4], k4A[4], k3B[4], k4B[4];   // k4,k5 history (hot, registers)
    uint  byA[4], byB[4];

    #pragma unroll
    for (int nt = 0; nt < 2; ++nt) {
        f32x4 va = *(const f32x4*)(x_in + (size_t)sidxA*D + nt*16 + quad*4);
        f32x4 vb = *(const f32x4*)(x_in + (size_t)sidxB*D + nt*16 + quad*4);
        #pragma unroll
        for (int r = 0; r < 4; ++r) { xA[nt*4 + r] = va[r]; xB[nt*4 + r] = vb[r]; }
    }

    const float dt = 0.125f;

    for (int bij = 0; bij < NB; ++bij) {
        const float* W1b = W1 + (size_t)bij * 2*D*H;
        const float* b1b = b1 + bij*H;
        const float* W2b = W2 + (size_t)bij * H*H;
        const float* b2b = b2 + bij*H;
        const float* W3b = W3 + (size_t)bij * H*D;
        const float* b3b = b3 + bij*D;

        __syncthreads();  // prior bijector done reading weights
        // ---- stage weights: fragment-order, k-permuted, f16, tanh-prescaled ----
        #pragma unroll 1
        for (int g = tid; g < 8*64; g += BT) {               // W1f (x TSCL)
            int nt = g >> 6, ln = g & 63, q = (ln >> 4) & 3, mr = ln & 15;
            f16 tmp[8];
            #pragma unroll
            for (int j = 0; j < 8; ++j) {
                int feat = ((j >> 2) << 4) + q*4 + (j & 3);  // phi1
                tmp[j] = (f16)(W1b[(size_t)(D + feat)*H + nt*16 + mr] * TSCL);
            }
            *(f16x8*)&sm.W1f[(size_t)g * 8] = *(f16x8*)tmp;
        }
        #pragma unroll 1
        for (int g = tid; g < 8*4*64; g += BT) {             // W2f (x TSCL)
            int nt = g >> 8, kt = (g >> 6) & 3, ln = g & 63, q = (ln >> 4) & 3, mr = ln & 15;
            f16 tmp[8];
            #pragma unroll
            for (int j = 0; j < 8; ++j) {
                int feat = (2*kt + (j >> 2))*16 + q*4 + (j & 3);  // phi
                tmp[j] = (f16)(W2b[(size_t)feat*H + nt*16 + mr] * TSCL);
            }
            *(f16x8*)&sm.W2f[(size_t)g * 8] = *(f16x8*)tmp;
        }
        #pragma unroll 1
        for (int g = tid; g < 2*4*64; g += BT) {             // W3f (unscaled)
            int nt = g >> 8, kt = (g >> 6) & 3, ln = g & 63, q = (ln >> 4) & 3, mr = ln & 15;
            f16 tmp[8];
            #pragma unroll
            for (int j = 0; j < 8; ++j) {
                int feat = (2*kt + (j >> 2))*16 + q*4 + (j & 3);  // phi
                tmp[j] = (f16)W3b[(size_t)feat*D + nt*16 + mr];
            }
            *(f16x8*)&sm.W3f[(size_t)g * 8] = *(f16x8*)tmp;
        }
        #pragma unroll 1
        for (int n = tid; n < H; n += BT) {                  // biases + t-fold sums (x TSCL)
            float s = 0.f;
            for (int i = 0; i < D; ++i) s += W1b[(size_t)i*H + n];
            sm.S1[n] = s * TSCL; sm.B1[n] = b1b[n] * TSCL; sm.B2[n] = b2b[n] * TSCL;
        }
        if (tid < D) sm.B3[tid] = b3b[tid];
        __syncthreads();

        // y := x  (packed)
        #pragma unroll
        for (int p = 0; p < 4; ++p) {
            byA[p] = pku(xA[2*p], xA[2*p + 1]);
            byB[p] = pku(xB[2*p], xB[2*p + 1]);
        }

        for (int step = 0; step < NSTEPS; ++step) {
            const float t0 = step * dt;
            #pragma unroll 1
            for (int s = 0; s < 6; ++s) {
                const float te = t0 + dt * CC[s];

                // ======== EVAL: two samples share every weight fragment ========
                // layer 1 (K=32): C init = (b1 + te*S1)*TSCL. Output built
                // DIRECTLY as the 4 L2 B-fragments (frag ktg = L1 nt 2ktg,2ktg+1).
                f16x8 fA1[4], fB1[4];
                {
                    union { f16x8 v; uint u[4]; } ba, bb;
                    ba.u[0] = byA[0]; ba.u[1] = byA[1]; ba.u[2] = byA[2]; ba.u[3] = byA[3];
                    bb.u[0] = byB[0]; bb.u[1] = byB[1]; bb.u[2] = byB[2]; bb.u[3] = byB[3];
                    #pragma unroll
                    for (int ktg = 0; ktg < 4; ++ktg) {
                        uint da[4], db[4];
                        #pragma unroll
                        for (int h = 0; h < 2; ++h) {
                            const int nt = ktg*2 + h;
                            f16x8 wf = *(const f16x8*)&sm.W1f[(nt*64 + lane)*8];
                            f32x4 bv = *(const f32x4*)&sm.B1[nt*16 + quad*4];
                            f32x4 sv = *(const f32x4*)&sm.S1[nt*16 + quad*4];
                            f32x4 ci;
                            #pragma unroll
                            for (int r = 0; r < 4; ++r) ci[r] = fmaf(te, sv[r], bv[r]);
                            f32x4 accA = __builtin_amdgcn_mfma_f32_16x16x32_f16(wf, ba.v, ci, 0, 0, 0);
                            f32x4 accB = __builtin_amdgcn_mfma_f32_16x16x32_f16(wf, bb.v, ci, 0, 0, 0);
                            da[h*2+0] = tanh_pk(accA[0], accA[1]);
                            da[h*2+1] = tanh_pk(accA[2], accA[3]);
                            db[h*2+0] = tanh_pk(accB[0], accB[1]);
                            db[h*2+1] = tanh_pk(accB[2], accB[3]);
                        }
                        uintx4 ua = {da[0], da[1], da[2], da[3]};
                        uintx4 ub = {db[0], db[1], db[2], db[3]};
                        fA1[ktg] = __builtin_bit_cast(f16x8, ua);
                        fB1[ktg] = __builtin_bit_cast(f16x8, ub);
                    }
                }
                // layer 2 (K=128) with layer 3 FUSED: each completed ph2
                // fragment (per ktg) feeds its 4 L3 MFMAs immediately and dies.
                float kdA[8], kdB[8];
                {
                    f32x4 a3A[2], a3B[2];
                    #pragma unroll
                    for (int n3 = 0; n3 < 2; ++n3) {
                        f32x4 c = *(const f32x4*)&sm.B3[n3*16 + quad*4];
                        a3A[n3] = c; a3B[n3] = c;
                    }
                    #pragma unroll 1
                    for (int ktg = 0; ktg < 4; ++ktg) {
                        uint da[4], db[4];
                        #pragma unroll
                        for (int h = 0; h < 2; ++h) {
                            const int nt = ktg*2 + h;
                            f32x4 c0 = *(const f32x4*)&sm.B2[nt*16 + quad*4];
                            f32x4 accA = c0, accB = c0;
                            #pragma unroll
                            for (int kt2 = 0; kt2 < 4; ++kt2) {
                                f16x8 wf = *(const f16x8*)&sm.W2f[((nt*4 + kt2)*64 + lane)*8];
                                accA = __builtin_amdgcn_mfma_f32_16x16x32_f16(wf, fA1[kt2], accA, 0, 0, 0);
                                accB = __builtin_amdgcn_mfma_f32_16x16x32_f16(wf, fB1[kt2], accB, 0, 0, 0);
                            }
                            da[h*2+0] = tanh_pk(accA[0], accA[1]);
                            da[h*2+1] = tanh_pk(accA[2], accA[3]);
                            db[h*2+0] = tanh_pk(accB[0], accB[1]);
                            db[h*2+1] = tanh_pk(accB[2], accB[3]);
                        }
                        uintx4 ua = {da[0], da[1], da[2], da[3]};
                        uintx4 ub = {db[0], db[1], db[2], db[3]};
                        f16x8 fra = __builtin_bit_cast(f16x8, ua);
                        f16x8 frb = __builtin_bit_cast(f16x8, ub);
                        #pragma unroll
                        for (int n3 = 0; n3 < 2; ++n3) {
                            f16x8 wf3 = *(const f16x8*)&sm.W3f[((n3*4 + ktg)*64 + lane)*8];
                            a3A[n3] = __builtin_amdgcn_mfma_f32_16x16x32_f16(wf3, fra, a3A[n3], 0, 0, 0);
                            a3B[n3] = __builtin_amdgcn_mfma_f32_16x16x32_f16(wf3, frb, a3B[n3], 0, 0, 0);
                        }
                    }
                    #pragma unroll
                    for (int n3 = 0; n3 < 2; ++n3)
                        #pragma unroll
                        for (int r = 0; r < 4; ++r) {
                            kdA[n3*4 + r] = a3A[n3][r];
                            kdB[n3*4 + r] = a3B[n3][r];
                        }
                }

                // ===== DOPRI combine; k1..k3 history in LDS stash, k4/k5 in
                // registers. Each thread touches only its own stash slots. =====
                switch (s) {
                case 0:
                    #pragma unroll
                    for (int j = 0; j < 4; ++j) {
                        sm.KS[0][0][j][tid] = pku(kdA[2*j], kdA[2*j+1]);
                        byA[j] = pku(fmaf(dt*0.2f, kdA[2*j],   xA[2*j]),
                                     fmaf(dt*0.2f, kdA[2*j+1], xA[2*j+1]));
                        sm.KS[0][1][j][tid] = pku(kdB[2*j], kdB[2*j+1]);
                        byB[j] = pku(fmaf(dt*0.2f, kdB[2*j],   xB[2*j]),
                                     fmaf(dt*0.2f, kdB[2*j+1], xB[2*j+1]));
                    }
                    break;
                case 1:
                    #pragma unroll
                    for (int j = 0; j < 4; ++j) {
                        uint a0 = sm.KS[0][0][j][tid];
                        sm.KS[1][0][j][tid] = pku(kdA[2*j], kdA[2*j+1]);
                        byA[j] = pku(xA[2*j]   + dt*((3.f/40.f)*lo32(a0) + (9.f/40.f)*kdA[2*j]),
                                     xA[2*j+1] + dt*((3.f/40.f)*hi32(a0) + (9.f/40.f)*kdA[2*j+1]));
                        uint b0 = sm.KS[0][1][j][tid];
                        sm.KS[1][1][j][tid] = pku(kdB[2*j], kdB[2*j+1]);
                        byB[j] = pku(xB[2*j]   + dt*((3.f/40.f)*lo32(b0) + (9.f/40.f)*kdB[2*j]),
                                     xB[2*j+1] + dt*((3.f/40.f)*hi32(b0) + (9.f/40.f)*kdB[2*j+1]));
                    }
                    break;
                case 2:
                    #pragma unroll
                    for (int j = 0; j < 4; ++j) {
                        uint a0 = sm.KS[0][0][j][tid], a1 = sm.KS[1][0][j][tid];
                        sm.KS[2][0][j][tid] = pku(kdA[2*j], kdA[2*j+1]);
                        byA[j] = pku(xA[2*j]   + dt*((44.f/45.f)*lo32(a0) - (56.f/15.f)*lo32(a1) + (32.f/9.f)*kdA[2*j]),
                                     xA[2*j+1] + dt*((44.f/45.f)*hi32(a0) - (56.f/15.f)*hi32(a1) + (32.f/9.f)*kdA[2*j+1]));
                        uint b0 = sm.KS[0][1][j][tid], b1 = sm.KS[1][1][j][tid];
                        sm.KS[2][1][j][tid] = pku(kdB[2*j], kdB[2*j+1]);
                        byB[j] = pku(xB[2*j]   + dt*((44.f/45.f)*lo32(b0) - (56.f/15.f)*lo32(b1) + (32.f/9.f)*kdB[2*j]),
                                     xB[2*j+1] + dt*((44.f/45.f)*hi32(b0) - (56.f/15.f)*hi32(b1) + (32.f/9.f)*kdB[2*j+1]));
                    }
                    break;
                case 3:
                    #pragma unroll
                    for (int j = 0; j < 4; ++j) {
                        uint a0 = sm.KS[0][0][j][tid], a1 = sm.KS[1][0][j][tid], a2 = sm.KS[2][0][j][tid];
                        k3A[j] = pku(kdA[2*j], kdA[2*j+1]);
                        byA[j] = pku(xA[2*j]   + dt*((19372.f/6561.f)*lo32(a0) - (25360.f/2187.f)*lo32(a1)
                                                   + (64448.f/6561.f)*lo32(a2) - (212.f/729.f)*kdA[2*j]),
                                     xA[2*j+1] + dt*((19372.f/6561.f)*hi32(a0) - (25360.f/2187.f)*hi32(a1)
                                                   + (64448.f/6561.f)*hi32(a2) - (212.f/729.f)*kdA[2*j+1]));
                        uint b0 = sm.KS[0][1][j][tid], b1 = sm.KS[1][1][j][tid], b2 = sm.KS[2][1][j][tid];
                        k3B[j] = pku(kdB[2*j], kdB[2*j+1]);
                        byB[j] = pku(xB[2*j]   + dt*((19372.f/6561.f)*lo32(b0) - (25360.f/2187.f)*lo32(b1)
                                                   + (64448.f/6561.f)*lo32(b2) - (212.f/729.f)*kdB[2*j]),
                                     xB[2*j+1] + dt*((19372.f/6561.f)*hi32(b0) - (25360.f/2187.f)*hi32(b1)
                                                   + (64448.f/6561.f)*hi32(b2) - (212.f/729.f)*kdB[2*j+1]));
                    }
                    break;
                case 4:
                    #pragma unroll
                    for (int j = 0; j < 4; ++j) {
                        uint a0 = sm.KS[0][0][j][tid], a1 = sm.KS[1][0][j][tid], a2 = sm.KS[2][0][j][tid];
                        k4A[j] = pku(kdA[2*j], kdA[2*j+1]);
                        byA[j] = pku(xA[2*j]   + dt*((9017.f/3168.f)*lo32(a0) - (355.f/33.f)*lo32(a1)
                                                   + (46732.f/5247.f)*lo32(a2) + (49.f/176.f)*lo32(k3A[j])
                                                   - (5103.f/18656.f)*kdA[2*j]),
                                     xA[2*j+1] + dt*((9017.f/3168.f)*hi32(a0) - (355.f/33.f)*hi32(a1)
                                                   + (46732.f/5247.f)*hi32(a2) + (49.f/176.f)*hi32(k3A[j])
                                                   - (5103.f/18656.f)*kdA[2*j+1]));
                        uint b0 = sm.KS[0][1][j][tid], b1 = sm.KS[1][1][j][tid], b2 = sm.KS[2][1][j][tid];
                        k4B[j] = pku(kdB[2*j], kdB[2*j+1]);
                        byB[j] = pku(xB[2*j]   + dt*((9017.f/3168.f)*lo32(b0) - (355.f/33.f)*lo32(b1)
                                                   + (46732.f/5247.f)*lo32(b2) + (49.f/176.f)*lo32(k3B[j])
                                                   - (5103.f/18656.f)*kdB[2*j]),
                                     xB[2*j+1] + dt*((9017.f/3168.f)*hi32(b0) - (355.f/33.f)*hi32(b1)
                                                   + (46732.f/5247.f)*hi32(b2) + (49.f/176.f)*hi32(k3B[j])
                                                   - (5103.f/18656.f)*kdB[2*j+1]));
                    }
                    break;
                default:
                    #pragma unroll
                    for (int j = 0; j < 4; ++j) {
                        uint a0 = sm.KS[0][0][j][tid], a2 = sm.KS[2][0][j][tid];
                        float xa = xA[2*j]   + dt*((35.f/384.f)*lo32(a0) + (500.f/1113.f)*lo32(a2)
                                                 + (125.f/192.f)*lo32(k3A[j]) - (2187.f/6784.f)*lo32(k4A[j])
                                                 + (11.f/84.f)*kdA[2*j]);
                        float xb = xA[2*j+1] + dt*((35.f/384.f)*hi32(a0) + (500.f/1113.f)*hi32(a2)
                                                 + (125.f/192.f)*hi32(k3A[j]) - (2187.f/6784.f)*hi32(k4A[j])
                                                 + (11.f/84.f)*kdA[2*j+1]);
                        xA[2*j] = xa; xA[2*j+1] = xb;
                        byA[j] = pku(xa, xb);
                        uint b0 = sm.KS[0][1][j][tid], b2 = sm.KS[2][1][j][tid];
                        float xc = xB[2*j]   + dt*((35.f/384.f)*lo32(b0) + (500.f/1113.f)*lo32(b2)
                                                 + (125.f/192.f)*lo32(k3B[j]) - (2187.f/6784.f)*lo32(k4B[j])
                                                 + (11.f/84.f)*kdB[2*j]);
                        float xd = xB[2*j+1] + dt*((35.f/384.f)*hi32(b0) + (500.f/1113.f)*hi32(b2)
                                                 + (125.f/192.f)*hi32(k3B[j]) - (2187.f/6784.f)*hi32(k4B[j])
                                                 + (11.f/84.f)*kdB[2*j+1]);
                        xB[2*j] = xc; xB[2*j+1] = xd;
                        byB[j] = pku(xc, xd);
                    }
                    break;
                }
            } // stages
        } // steps
    } // bijectors

    #pragma unroll
    for (int nt = 0; nt < 2; ++nt) {
        f32x4 va, vb;
        #pragma unroll
        for (int r = 0; r < 4; ++r) { va[r] = xA[nt*4 + r]; vb[r] = xB[nt*4 + r]; }
        *(f32x4*)(out + (size_t)sidxA*D + nt*16 + quad*4) = va;
        *(f32x4*)(out + (size_t)sidxB*D + nt*16 + quad*4) = vb;
    }
}

extern "C" void kernel_launch(void* const* d_in, const int* in_sizes, int n_in,
                              void* d_out, int out_size, void* d_ws, size_t ws_size,
                              hipStream_t stream) {
    (void)d_ws; (void)ws_size; (void)n_in; (void)out_size;
    const float* x  = (const float*)d_in[0];
    const float* W1 = (const float*)d_in[1];
    const float* b1 = (const float*)d_in[2];
    const float* W2 = (const float*)d_in[3];
    const float* b2 = (const float*)d_in[4];
    const float* W3 = (const float*)d_in[5];
    const float* b3 = (const float*)d_in[6];
    float* out = (float*)d_out;

    const int n = in_sizes[0] / D;          // 65536 samples
    const int grid = n / 128;               // 512 blocks (128 samples each), exact
    ffjord_mfma<<<grid, BT, 0, stream>>>(x, W1, b1, W2, b2, W3, b3, out);
}